// Round 3
// baseline (335.857 us; speedup 1.0000x reference)
//
#include <hip/hip_runtime.h>
#include <hip/hip_bf16.h>

#define IN_DIM 256
#define OUT_DIM 64
#define CHUNK 4096
#define BSH 8      // bucket = dst >> 8 (256 nodes/bucket)
#define P2CAP 6144

typedef short bf16x8 __attribute__((ext_vector_type(8)));
typedef float f32x4 __attribute__((ext_vector_type(4)));

__device__ inline unsigned short f2bf(float x) {
  unsigned int u = __float_as_uint(x);
  return (unsigned short)((u + 0x7FFFu + ((u >> 16) & 1u)) >> 16);
}

// ---- prep: W [256][64] fp32 -> Wbf in MFMA-fragment-major bf16 -------------
// frag f = (kc,ct,lane): Wbf[f*8 + j] = W[kc*32+(lane>>4)*8+j][ct*16+(lane&15)]
// Also zeroes tot[] (per-bucket edge counts accumulated by k_part atomics).
__global__ __launch_bounds__(256) void k_prep(const float* __restrict__ W,
                                              unsigned short* __restrict__ Wbf,
                                              int* __restrict__ tot) {
  int f = blockIdx.x * 256 + threadIdx.x;  // 0..2047
  if (f < 512) tot[f] = 0;
  int kc = f >> 8, ct = (f >> 6) & 3, q = (f >> 4) & 3, nq = f & 15;
  int col = ct * 16 + nq, k0 = kc * 32 + q * 8;
  unsigned short v[8];
#pragma unroll
  for (int j = 0; j < 8; ++j) v[j] = f2bf(W[(size_t)(k0 + j) * OUT_DIM + col]);
  *(uint4*)(Wbf + (size_t)f * 8) = *(uint4*)v;
}

// ---- GEMM: zb(bf16) = h @ W ; el = z@a1 ; er = z@a2 -------------------------
// 256 thr = 4 waves, 64 rows/block. A staged in LDS via coalesced float4 reads;
// W fragments read directly from frag-major global (L2-hot 32 KB).
__global__ __launch_bounds__(256) void k_gemm(const float* __restrict__ h,
                                              const unsigned short* __restrict__ Wbf,
                                              const float* __restrict__ a,
                                              unsigned short* __restrict__ zb,
                                              float* __restrict__ el,
                                              float* __restrict__ er, int n) {
  __shared__ unsigned short Ab[64][264];  // 33 KB; +8 pad keeps writes 2-way max
  const int t = threadIdx.x;
  const int base = blockIdx.x * 64;

#pragma unroll
  for (int i = 0; i < 16; ++i) {
    int f = i * 256 + t;
    int r = f >> 6, c4 = f & 63;
    int row = base + r;
    float4 v = make_float4(0.f, 0.f, 0.f, 0.f);
    if (row < n) v = *(const float4*)(h + (size_t)row * IN_DIM + c4 * 4);
    unsigned int p0 = (unsigned int)f2bf(v.x) | ((unsigned int)f2bf(v.y) << 16);
    unsigned int p1 = (unsigned int)f2bf(v.z) | ((unsigned int)f2bf(v.w) << 16);
    *(uint2*)&Ab[r][c4 * 4] = make_uint2(p0, p1);
  }
  __syncthreads();

  const int w = t >> 6, lane = t & 63, nq = lane & 15, q = lane >> 4;

  f32x4 acc[4];
#pragma unroll
  for (int ct = 0; ct < 4; ++ct) acc[ct] = (f32x4){0.f, 0.f, 0.f, 0.f};

#pragma unroll
  for (int kc = 0; kc < 8; ++kc) {
    bf16x8 af = *(const bf16x8*)&Ab[w * 16 + nq][kc * 32 + q * 8];
#pragma unroll
    for (int ct = 0; ct < 4; ++ct) {
      bf16x8 bfr = *(const bf16x8*)(Wbf + (size_t)((kc * 4 + ct) * 64 + lane) * 8);
      acc[ct] = __builtin_amdgcn_mfma_f32_16x16x32_bf16(af, bfr, acc[ct], 0, 0, 0);
    }
  }

  float a1[4], a2[4];
#pragma unroll
  for (int ct = 0; ct < 4; ++ct) {
    a1[ct] = a[ct * 16 + nq];
    a2[ct] = a[OUT_DIM + ct * 16 + nq];
  }
#pragma unroll
  for (int r = 0; r < 4; ++r) {
    int orow = base + w * 16 + q * 4 + r;
    float p1 = 0.f, p2 = 0.f;
#pragma unroll
    for (int ct = 0; ct < 4; ++ct) {
      float v = acc[ct][r];
      p1 += v * a1[ct];
      p2 += v * a2[ct];
      if (orow < n) zb[(size_t)orow * OUT_DIM + ct * 16 + nq] = f2bf(v);
    }
    p1 += __shfl_xor(p1, 1); p1 += __shfl_xor(p1, 2);
    p1 += __shfl_xor(p1, 4); p1 += __shfl_xor(p1, 8);
    p2 += __shfl_xor(p2, 1); p2 += __shfl_xor(p2, 2);
    p2 += __shfl_xor(p2, 4); p2 += __shfl_xor(p2, 8);
    if (orow < n && nq == 0) { el[orow] = p1; er[orow] = p2; }
  }
}

// ---- pass-1: per-chunk in-LDS bucket sort; ALL global writes coalesced ------
// Block b sorts its 4096 edges by bucket into stage[], dumps to pairs[b*4096..]
// (contiguous), writes lofs[b][0..nbuck] (per-chunk bucket offsets, coalesced),
// and atomicAdds per-bucket counts into tot[] (fire-and-forget, 391 addrs).
__global__ __launch_bounds__(256) void k_part(const int* __restrict__ src,
                                              const int* __restrict__ dst,
                                              int* __restrict__ pairs,
                                              int* __restrict__ lofs,
                                              int* __restrict__ tot, int E,
                                              int nbuck, int b1) {
  __shared__ int hist[512];
  __shared__ int excl[512];
  __shared__ int cur[512];
  __shared__ int stage[CHUNK];
  __shared__ int wtot[4];
  const int t = threadIdx.x, b = blockIdx.x;
  const int beg = b * CHUNK;
  const int cnt = min(CHUNK, E - beg);

  hist[t] = 0;
  hist[t + 256] = 0;
  __syncthreads();

  int dv[16], sv[16];
#pragma unroll
  for (int k = 0; k < 16; ++k) {
    int i = k * 256 + t;
    dv[k] = -1;
    if (i < cnt) {
      dv[k] = dst[beg + i];
      sv[k] = src[beg + i];
      atomicAdd(&hist[dv[k] >> BSH], 1);
    }
  }
  __syncthreads();

  // exclusive scan of hist[0..511]: 2 contiguous elements per thread.
  {
    int d0 = hist[2 * t], d1 = hist[2 * t + 1];
    int tsum = d0 + d1;
    int lane = t & 63, w = t >> 6;
    int incl = tsum;
    for (int o = 1; o < 64; o <<= 1) {
      int u = __shfl_up(incl, o);
      if (lane >= o) incl += u;
    }
    if (lane == 63) wtot[w] = incl;
    __syncthreads();
    int woff = 0;
    for (int i = 0; i < 4; ++i)
      if (i < w) woff += wtot[i];
    int ex = woff + incl - tsum;
    excl[2 * t] = ex;
    excl[2 * t + 1] = ex + d0;
    cur[2 * t] = ex;
    cur[2 * t + 1] = ex + d0;
  }
  __syncthreads();

  // LDS scatter (banked, cheap) then coalesced global dump.
#pragma unroll
  for (int k = 0; k < 16; ++k) {
    if (dv[k] >= 0) {
      int bk = dv[k] >> BSH;
      int r = atomicAdd(&cur[bk], 1);
      stage[r] = ((dv[k] & ((1 << BSH) - 1)) << 24) | sv[k];
    }
  }
  __syncthreads();
#pragma unroll
  for (int k = 0; k < 16; ++k) {
    int i = k * 256 + t;
    if (i < cnt) pairs[beg + i] = stage[i];
  }
  // lofs row: nbuck+1 entries (excl[nbuck] == cnt).
  for (int i = t; i <= nbuck; i += 256) lofs[(size_t)b * (nbuck + 1) + i] = excl[i];
  for (int i = t; i < nbuck; i += 256)
    if (hist[i]) atomicAdd(&tot[i], hist[i]);
}

// ---- tiny scan over per-bucket totals -> pbeg (exclusive) -------------------
__global__ __launch_bounds__(256) void k_scanT(const int* __restrict__ tot,
                                               int* __restrict__ pbeg, int nbuck) {
  __shared__ int wtot[4];
  int t = threadIdx.x;
  int d0 = (2 * t < nbuck) ? tot[2 * t] : 0;
  int d1 = (2 * t + 1 < nbuck) ? tot[2 * t + 1] : 0;
  int tsum = d0 + d1;
  int lane = t & 63, w = t >> 6;
  int incl = tsum;
  for (int o = 1; o < 64; o <<= 1) {
    int u = __shfl_up(incl, o);
    if (lane >= o) incl += u;
  }
  if (lane == 63) wtot[w] = incl;
  __syncthreads();
  int woff = 0;
  for (int i = 0; i < 4; ++i)
    if (i < w) woff += wtot[i];
  int ex = woff + incl - tsum;
  pbeg[2 * t] = ex;
  pbeg[2 * t + 1] = ex + d0;
}

// ---- pass-2: per-bucket segment-gather + in-LDS counting sort + off[] -------
// Block b = bucket b. Gathers its 391 per-chunk segments (scattered READS,
// latency-hidden), counting-sorts by local dst in LDS, dumps ssrc coalesced.
__global__ __launch_bounds__(256) void k_p2(const int* __restrict__ pairs,
                                            const int* __restrict__ lofs,
                                            const int* __restrict__ tot,
                                            const int* __restrict__ pbeg,
                                            int* __restrict__ ssrc,
                                            int* __restrict__ off, int E, int n,
                                            int nbuck, int b1) {
  __shared__ int seg0[512];
  __shared__ int slen[512];
  __shared__ int deg[256];
  __shared__ int loff[256];
  __shared__ int cur[256];
  __shared__ int stage[P2CAP];
  __shared__ int wtot[4];
  const int t = threadIdx.x, b = blockIdx.x;
  const int beg = pbeg[b];
  const int cntb = tot[b];

  // per-chunk segment (start,len) for this bucket.
  for (int c = t; c < b1; c += 256) {
    int s0 = lofs[(size_t)c * (nbuck + 1) + b];
    int s1 = lofs[(size_t)c * (nbuck + 1) + b + 1];
    seg0[c] = c * CHUNK + s0;
    slen[c] = s1 - s0;
  }
  deg[t] = 0;
  __syncthreads();

  const int w = t >> 6, li = t & 63;
  // pass A: degree histogram over local dst (gather segments, wave per chunk).
  for (int c = w; c < b1; c += 4) {
    int s0 = seg0[c], ln = slen[c];
    for (int k0 = 0; k0 < ln; k0 += 64) {
      if (li < ln - k0) {
        int v = pairs[s0 + k0 + li];
        atomicAdd(&deg[((unsigned)v) >> 24], 1);
      }
    }
  }
  __syncthreads();

  // exclusive scan of deg[0..255].
  {
    int v = deg[t];
    int inc = v;
    for (int o = 1; o < 64; o <<= 1) {
      int u = __shfl_up(inc, o);
      if (li >= o) inc += u;
    }
    if (li == 63) wtot[w] = inc;
    __syncthreads();
    int woff = 0;
    for (int i = 0; i < 4; ++i)
      if (i < w) woff += wtot[i];
    int ex = woff + inc - v;
    loff[t] = ex;
    cur[t] = ex;
  }
  __syncthreads();

  // pass B: re-gather (L2-hot) and scatter into stage by node.
  for (int c = w; c < b1; c += 4) {
    int s0 = seg0[c], ln = slen[c];
    for (int k0 = 0; k0 < ln; k0 += 64) {
      if (li < ln - k0) {
        int v = pairs[s0 + k0 + li];
        int r = atomicAdd(&cur[((unsigned)v) >> 24], 1);
        if (r < P2CAP) stage[r] = v & 0xFFFFFF;
      }
    }
  }
  __syncthreads();

  for (int i = t; i < cntb; i += 256) ssrc[beg + i] = stage[i];
  int node = (b << BSH) + t;
  if (node <= n) off[node] = beg + loff[t];
}

// ------- fused aggregate: x4-unrolled gather for MLP --------------------------
__global__ __launch_bounds__(256) void k_agg(const int* __restrict__ off,
                                             const int* __restrict__ ssrc,
                                             const float* __restrict__ el,
                                             const float* __restrict__ er,
                                             const unsigned short* __restrict__ zb,
                                             float* __restrict__ out, int N) {
  int t = threadIdx.x;
  int node = blockIdx.x * 16 + (t >> 4);
  if (node >= N) return;
  int cq = (t & 15) * 4;
  int beg = off[node], end = off[node + 1];
  float erd = er[node];
  float ax = 0.f, ay = 0.f, az = 0.f, aw = 0.f, ssum = 0.f;
  int j = beg;
  for (; j + 4 <= end; j += 4) {
    int s0 = ssrc[j], s1 = ssrc[j + 1], s2 = ssrc[j + 2], s3 = ssrc[j + 3];
    uint2 z0 = *(const uint2*)(zb + (s0 << 6) + cq);
    uint2 z1 = *(const uint2*)(zb + (s1 << 6) + cq);
    uint2 z2 = *(const uint2*)(zb + (s2 << 6) + cq);
    uint2 z3 = *(const uint2*)(zb + (s3 << 6) + cq);
    float x0 = el[s0] + erd, x1 = el[s1] + erd;
    float x2 = el[s2] + erd, x3 = el[s3] + erd;
    x0 = x0 > 0.f ? x0 : 0.01f * x0;
    x1 = x1 > 0.f ? x1 : 0.01f * x1;
    x2 = x2 > 0.f ? x2 : 0.01f * x2;
    x3 = x3 > 0.f ? x3 : 0.01f * x3;
    float e0 = __expf(x0), e1 = __expf(x1), e2 = __expf(x2), e3 = __expf(x3);
    ssum += (e0 + e1) + (e2 + e3);
    ax += e0 * __uint_as_float(z0.x << 16) + e1 * __uint_as_float(z1.x << 16) +
          e2 * __uint_as_float(z2.x << 16) + e3 * __uint_as_float(z3.x << 16);
    ay += e0 * __uint_as_float(z0.x & 0xFFFF0000u) + e1 * __uint_as_float(z1.x & 0xFFFF0000u) +
          e2 * __uint_as_float(z2.x & 0xFFFF0000u) + e3 * __uint_as_float(z3.x & 0xFFFF0000u);
    az += e0 * __uint_as_float(z0.y << 16) + e1 * __uint_as_float(z1.y << 16) +
          e2 * __uint_as_float(z2.y << 16) + e3 * __uint_as_float(z3.y << 16);
    aw += e0 * __uint_as_float(z0.y & 0xFFFF0000u) + e1 * __uint_as_float(z1.y & 0xFFFF0000u) +
          e2 * __uint_as_float(z2.y & 0xFFFF0000u) + e3 * __uint_as_float(z3.y & 0xFFFF0000u);
  }
  for (; j < end; ++j) {
    int s = ssrc[j];
    uint2 zv = *(const uint2*)(zb + (s << 6) + cq);
    float x = el[s] + erd;
    x = x > 0.f ? x : 0.01f * x;
    float ex = __expf(x);
    ssum += ex;
    ax += ex * __uint_as_float(zv.x << 16);
    ay += ex * __uint_as_float(zv.x & 0xFFFF0000u);
    az += ex * __uint_as_float(zv.y << 16);
    aw += ex * __uint_as_float(zv.y & 0xFFFF0000u);
  }
  float4 o = make_float4(0.f, 0.f, 0.f, 0.f);
  if (end > beg) {
    float inv = 1.f / ssum;
    ax *= inv; ay *= inv; az *= inv; aw *= inv;
    o.x = ax > 0.f ? ax : __expf(ax) - 1.f;
    o.y = ay > 0.f ? ay : __expf(ay) - 1.f;
    o.z = az > 0.f ? az : __expf(az) - 1.f;
    o.w = aw > 0.f ? aw : __expf(aw) - 1.f;
  }
  *(float4*)(out + ((size_t)node << 6) + cq) = o;
}

extern "C" void kernel_launch(void* const* d_in, const int* in_sizes, int n_in,
                              void* d_out, int out_size, void* d_ws, size_t ws_size,
                              hipStream_t stream) {
  const float* h = (const float*)d_in[0];
  const float* W = (const float*)d_in[1];
  const float* a = (const float*)d_in[2];
  const int* src = (const int*)d_in[3];
  const int* dst = (const int*)d_in[4];
  const int n = in_sizes[0] / IN_DIM;  // 100000
  const int E = in_sizes[3];           // 1600000
  float* out = (float*)d_out;

  const int b1 = (E + CHUNK - 1) / CHUNK;         // 391
  const int nbuck = (n + (1 << BSH) - 1) >> BSH;  // 391

  char* ws = (char*)d_ws;
  auto alloc = [&](size_t bytes) {
    char* p = ws;
    ws += (bytes + 15) & ~(size_t)15;
    return p;
  };
  unsigned short* Wbf = (unsigned short*)alloc(16384 * 2);
  unsigned short* zb = (unsigned short*)alloc((size_t)n * OUT_DIM * 2);
  float* el = (float*)alloc((size_t)n * 4);
  float* er = (float*)alloc((size_t)n * 4);
  int* lofs = (int*)alloc((size_t)b1 * (nbuck + 1) * 4);
  int* tot = (int*)alloc(512 * 4);
  int* pbeg = (int*)alloc(512 * 4);
  int* off = (int*)alloc((size_t)(n + 1) * 4);
  int* pairs = (int*)alloc((size_t)b1 * CHUNK * 4);
  int* ssrc = (int*)alloc((size_t)E * 4);

  k_prep<<<8, 256, 0, stream>>>(W, Wbf, tot);
  k_gemm<<<(n + 63) / 64, 256, 0, stream>>>(h, Wbf, a, zb, el, er, n);
  k_part<<<b1, 256, 0, stream>>>(src, dst, pairs, lofs, tot, E, nbuck, b1);
  k_scanT<<<1, 256, 0, stream>>>(tot, pbeg, nbuck);
  k_p2<<<nbuck, 256, 0, stream>>>(pairs, lofs, tot, pbeg, ssrc, off, E, n, nbuck, b1);
  k_agg<<<(n + 15) / 16, 256, 0, stream>>>(off, ssrc, el, er, zb, out, n);
}

// Round 4
// 257.121 us; speedup vs baseline: 1.3062x; 1.3062x over previous
//
#include <hip/hip_runtime.h>
#include <hip/hip_bf16.h>

#define IN_DIM 256
#define OUT_DIM 64
#define CHUNK 8192
#define BSH 8      // bucket = dst >> 8 (256 nodes/bucket)
#define P2CAP 6144

typedef short bf16x8 __attribute__((ext_vector_type(8)));
typedef float f32x4 __attribute__((ext_vector_type(4)));

__device__ inline unsigned short f2bf(float x) {
  unsigned int u = __float_as_uint(x);
  return (unsigned short)((u + 0x7FFFu + ((u >> 16) & 1u)) >> 16);
}

// ---- prep: W [256][64] fp32 -> Wbf in MFMA-fragment-major bf16 -------------
// Also zeroes tot[] (per-bucket totals accumulated by k_gemm's hist tail).
__global__ __launch_bounds__(256) void k_prep(const float* __restrict__ W,
                                              unsigned short* __restrict__ Wbf,
                                              int* __restrict__ tot) {
  int f = blockIdx.x * 256 + threadIdx.x;  // 0..2047
  if (f < 512) tot[f] = 0;
  int kc = f >> 8, ct = (f >> 6) & 3, q = (f >> 4) & 3, nq = f & 15;
  int col = ct * 16 + nq, k0 = kc * 32 + q * 8;
  unsigned short v[8];
#pragma unroll
  for (int j = 0; j < 8; ++j) v[j] = f2bf(W[(size_t)(k0 + j) * OUT_DIM + col]);
  *(uint4*)(Wbf + (size_t)f * 8) = *(uint4*)v;
}

// ---- GEMM: zb(bf16) = h @ W ; el = z@a1 ; er = z@a2 -------------------------
// Tail: each block histograms 1024 edges' dst buckets in LDS, flushes to tot[].
__global__ __launch_bounds__(256) void k_gemm(const float* __restrict__ h,
                                              const unsigned short* __restrict__ Wbf,
                                              const float* __restrict__ a,
                                              unsigned short* __restrict__ zb,
                                              float* __restrict__ el,
                                              float* __restrict__ er, int n,
                                              const int* __restrict__ dst,
                                              int* __restrict__ tot, int E,
                                              int nbuck) {
  __shared__ unsigned short Ab[64][264];  // 33 KB; +8 pad keeps writes 2-way max
  __shared__ int hist[512];
  const int t = threadIdx.x;
  const int base = blockIdx.x * 64;

#pragma unroll
  for (int i = 0; i < 16; ++i) {
    int f = i * 256 + t;
    int r = f >> 6, c4 = f & 63;
    int row = base + r;
    float4 v = make_float4(0.f, 0.f, 0.f, 0.f);
    if (row < n) v = *(const float4*)(h + (size_t)row * IN_DIM + c4 * 4);
    unsigned int p0 = (unsigned int)f2bf(v.x) | ((unsigned int)f2bf(v.y) << 16);
    unsigned int p1 = (unsigned int)f2bf(v.z) | ((unsigned int)f2bf(v.w) << 16);
    *(uint2*)&Ab[r][c4 * 4] = make_uint2(p0, p1);
  }
  __syncthreads();

  const int w = t >> 6, lane = t & 63, nq = lane & 15, q = lane >> 4;

  f32x4 acc[4];
#pragma unroll
  for (int ct = 0; ct < 4; ++ct) acc[ct] = (f32x4){0.f, 0.f, 0.f, 0.f};

#pragma unroll
  for (int kc = 0; kc < 8; ++kc) {
    bf16x8 af = *(const bf16x8*)&Ab[w * 16 + nq][kc * 32 + q * 8];
#pragma unroll
    for (int ct = 0; ct < 4; ++ct) {
      bf16x8 bfr = *(const bf16x8*)(Wbf + (size_t)((kc * 4 + ct) * 64 + lane) * 8);
      acc[ct] = __builtin_amdgcn_mfma_f32_16x16x32_bf16(af, bfr, acc[ct], 0, 0, 0);
    }
  }

  float a1[4], a2[4];
#pragma unroll
  for (int ct = 0; ct < 4; ++ct) {
    a1[ct] = a[ct * 16 + nq];
    a2[ct] = a[OUT_DIM + ct * 16 + nq];
  }
#pragma unroll
  for (int r = 0; r < 4; ++r) {
    int orow = base + w * 16 + q * 4 + r;
    float p1 = 0.f, p2 = 0.f;
#pragma unroll
    for (int ct = 0; ct < 4; ++ct) {
      float v = acc[ct][r];
      p1 += v * a1[ct];
      p2 += v * a2[ct];
      if (orow < n) zb[(size_t)orow * OUT_DIM + ct * 16 + nq] = f2bf(v);
    }
    p1 += __shfl_xor(p1, 1); p1 += __shfl_xor(p1, 2);
    p1 += __shfl_xor(p1, 4); p1 += __shfl_xor(p1, 8);
    p2 += __shfl_xor(p2, 1); p2 += __shfl_xor(p2, 2);
    p2 += __shfl_xor(p2, 4); p2 += __shfl_xor(p2, 8);
    if (orow < n && nq == 0) { el[orow] = p1; er[orow] = p2; }
  }

  // fused per-bucket totals: 1024 edges per block (grid 1563 covers E=1.6M).
  hist[t] = 0;
  hist[t + 256] = 0;
  __syncthreads();
  int e0 = blockIdx.x * 1024 + t * 4;
  if (e0 + 4 <= E) {
    int4 d4 = *(const int4*)(dst + e0);
    atomicAdd(&hist[d4.x >> BSH], 1);
    atomicAdd(&hist[d4.y >> BSH], 1);
    atomicAdd(&hist[d4.z >> BSH], 1);
    atomicAdd(&hist[d4.w >> BSH], 1);
  } else {
#pragma unroll
    for (int k = 0; k < 4; ++k) {
      int e = e0 + k;
      if (e < E) atomicAdd(&hist[dst[e] >> BSH], 1);
    }
  }
  __syncthreads();
  for (int i = t; i < nbuck; i += 256)
    if (hist[i]) atomicAdd(&tot[i], hist[i]);
}

// ---- tiny scan: tot -> pbeg (exclusive) and seed gcur = pbeg ---------------
__global__ __launch_bounds__(256) void k_scanT(const int* __restrict__ tot,
                                               int* __restrict__ pbeg,
                                               int* __restrict__ gcur, int nbuck) {
  __shared__ int wtot[4];
  int t = threadIdx.x;
  int d0 = (2 * t < nbuck) ? tot[2 * t] : 0;
  int d1 = (2 * t + 1 < nbuck) ? tot[2 * t + 1] : 0;
  int tsum = d0 + d1;
  int lane = t & 63, w = t >> 6;
  int incl = tsum;
  for (int o = 1; o < 64; o <<= 1) {
    int u = __shfl_up(incl, o);
    if (lane >= o) incl += u;
  }
  if (lane == 63) wtot[w] = incl;
  __syncthreads();
  int woff = 0;
  for (int i = 0; i < 4; ++i)
    if (i < w) woff += wtot[i];
  int ex = woff + incl - tsum;
  pbeg[2 * t] = ex;
  gcur[2 * t] = ex;
  pbeg[2 * t + 1] = ex + d0;
  gcur[2 * t + 1] = ex + d0;
}

// ---- partition: LDS bucket-sort 8192-edge chunk, atomic-reserve runs, -------
// dump run-contiguous into bucket-major pairs[]. No scattered global stores.
__global__ __launch_bounds__(512) void k_part(const int* __restrict__ src,
                                              const int* __restrict__ dst,
                                              int* __restrict__ gcur,
                                              int* __restrict__ pairs, int E,
                                              int nbuck) {
  __shared__ int hist[512];
  __shared__ int excl[512];
  __shared__ int cur[512];
  __shared__ int rbase[512];
  __shared__ int stage[CHUNK];           // 32 KB
  __shared__ unsigned short sbk[CHUNK];  // 16 KB: bucket id per sorted slot
  __shared__ int wtot[8];
  const int t = threadIdx.x, b = blockIdx.x;
  const int beg = b * CHUNK;
  const int cnt = min(CHUNK, E - beg);

  hist[t] = 0;
  __syncthreads();

  int dv[16], sv[16];
#pragma unroll
  for (int k = 0; k < 16; ++k) {
    int i = k * 512 + t;
    dv[k] = -1;
    if (i < cnt) {
      dv[k] = dst[beg + i];
      sv[k] = src[beg + i];
      atomicAdd(&hist[dv[k] >> BSH], 1);
    }
  }
  __syncthreads();

  // exclusive scan of hist[512] (1 elem/thread, 8 waves) + run reservation.
  {
    int v = hist[t];
    int lane = t & 63, w = t >> 6;
    int incl = v;
    for (int o = 1; o < 64; o <<= 1) {
      int u = __shfl_up(incl, o);
      if (lane >= o) incl += u;
    }
    if (lane == 63) wtot[w] = incl;
    __syncthreads();
    int woff = 0;
    for (int i = 0; i < 8; ++i)
      if (i < w) woff += wtot[i];
    int ex = woff + incl - v;
    excl[t] = ex;
    cur[t] = ex;
    if (t < nbuck && v > 0) rbase[t] = atomicAdd(&gcur[t], v);
  }
  __syncthreads();

  // LDS scatter (banked) into bucket-sorted order.
#pragma unroll
  for (int k = 0; k < 16; ++k) {
    if (dv[k] >= 0) {
      int bk = dv[k] >> BSH;
      int r = atomicAdd(&cur[bk], 1);
      stage[r] = ((dv[k] & ((1 << BSH) - 1)) << 24) | sv[k];
      sbk[r] = (unsigned short)bk;
    }
  }
  __syncthreads();

  // dump: consecutive slots within a run -> consecutive global dest (coalesced).
  for (int i = t; i < cnt; i += 512) {
    int bk = sbk[i];
    pairs[rbase[bk] + (i - excl[bk])] = stage[i];
  }
}

// ---- fused pass-2 + aggregation: bucket sort in LDS, aggregate from LDS -----
__global__ __launch_bounds__(1024) void k_p2agg(const int* __restrict__ pairs,
                                                const int* __restrict__ tot,
                                                const int* __restrict__ pbeg,
                                                const float* __restrict__ el,
                                                const float* __restrict__ er,
                                                const unsigned short* __restrict__ zb,
                                                float* __restrict__ out, int n) {
  __shared__ int deg[256];
  __shared__ int loff[257];
  __shared__ int cur[256];
  __shared__ int stage[P2CAP];
  __shared__ int wtot[4];
  const int t = threadIdx.x, b = blockIdx.x;
  const int beg = pbeg[b];
  const int cnt = tot[b];

  if (t < 256) deg[t] = 0;
  __syncthreads();

  // single coalesced read of this bucket's edges into registers + degree hist.
  int pv[6];
#pragma unroll
  for (int k = 0; k < 6; ++k) {
    int i = k * 1024 + t;
    pv[k] = 0;
    if (i < cnt) {
      pv[k] = pairs[beg + i];
      atomicAdd(&deg[((unsigned)pv[k]) >> 24], 1);
    }
  }
  __syncthreads();

  // exclusive scan of deg[256] by the first 4 waves.
  int v = 0, inc = 0;
  const int lane = t & 63, w = t >> 6;
  if (t < 256) {
    v = deg[t];
    inc = v;
    for (int o = 1; o < 64; o <<= 1) {
      int u = __shfl_up(inc, o);
      if (lane >= o) inc += u;
    }
    if (lane == 63) wtot[w] = inc;
  }
  __syncthreads();
  if (t < 256) {
    int woff = 0;
    for (int i = 0; i < 4; ++i)
      if (i < w) woff += wtot[i];
    int ex = woff + inc - v;
    loff[t] = ex;
    cur[t] = ex;
    if (t == 255) loff[256] = ex + v;
  }
  __syncthreads();

  // scatter into node-sorted LDS stage (payload = src only).
#pragma unroll
  for (int k = 0; k < 6; ++k) {
    int i = k * 1024 + t;
    if (i < cnt) {
      int r = atomicAdd(&cur[((unsigned)pv[k]) >> 24], 1);
      if (r < P2CAP) stage[r] = pv[k] & 0xFFFFFF;
    }
  }
  __syncthreads();

  // aggregation: 64 groups x 16 lanes; 4 rounds cover 256 nodes.
  const int g = t >> 4;
  const int cq = (t & 15) * 4;
#pragma unroll
  for (int round = 0; round < 4; ++round) {
    int nl = round * 64 + g;
    int node = (b << BSH) + nl;
    if (node >= n) continue;
    int jb = loff[nl], je = loff[nl + 1];
    float erd = er[node];
    float ax = 0.f, ay = 0.f, az = 0.f, aw = 0.f, ssum = 0.f;
    int j = jb;
    for (; j + 4 <= je; j += 4) {
      int s0 = stage[j], s1 = stage[j + 1], s2 = stage[j + 2], s3 = stage[j + 3];
      uint2 z0 = *(const uint2*)(zb + (s0 << 6) + cq);
      uint2 z1 = *(const uint2*)(zb + (s1 << 6) + cq);
      uint2 z2 = *(const uint2*)(zb + (s2 << 6) + cq);
      uint2 z3 = *(const uint2*)(zb + (s3 << 6) + cq);
      float x0 = el[s0] + erd, x1 = el[s1] + erd;
      float x2 = el[s2] + erd, x3 = el[s3] + erd;
      x0 = x0 > 0.f ? x0 : 0.01f * x0;
      x1 = x1 > 0.f ? x1 : 0.01f * x1;
      x2 = x2 > 0.f ? x2 : 0.01f * x2;
      x3 = x3 > 0.f ? x3 : 0.01f * x3;
      float e0 = __expf(x0), e1 = __expf(x1), e2 = __expf(x2), e3 = __expf(x3);
      ssum += (e0 + e1) + (e2 + e3);
      ax += e0 * __uint_as_float(z0.x << 16) + e1 * __uint_as_float(z1.x << 16) +
            e2 * __uint_as_float(z2.x << 16) + e3 * __uint_as_float(z3.x << 16);
      ay += e0 * __uint_as_float(z0.x & 0xFFFF0000u) + e1 * __uint_as_float(z1.x & 0xFFFF0000u) +
            e2 * __uint_as_float(z2.x & 0xFFFF0000u) + e3 * __uint_as_float(z3.x & 0xFFFF0000u);
      az += e0 * __uint_as_float(z0.y << 16) + e1 * __uint_as_float(z1.y << 16) +
            e2 * __uint_as_float(z2.y << 16) + e3 * __uint_as_float(z3.y << 16);
      aw += e0 * __uint_as_float(z0.y & 0xFFFF0000u) + e1 * __uint_as_float(z1.y & 0xFFFF0000u) +
            e2 * __uint_as_float(z2.y & 0xFFFF0000u) + e3 * __uint_as_float(z3.y & 0xFFFF0000u);
    }
    for (; j < je; ++j) {
      int s = stage[j];
      uint2 zv = *(const uint2*)(zb + (s << 6) + cq);
      float x = el[s] + erd;
      x = x > 0.f ? x : 0.01f * x;
      float ex = __expf(x);
      ssum += ex;
      ax += ex * __uint_as_float(zv.x << 16);
      ay += ex * __uint_as_float(zv.x & 0xFFFF0000u);
      az += ex * __uint_as_float(zv.y << 16);
      aw += ex * __uint_as_float(zv.y & 0xFFFF0000u);
    }
    float4 o = make_float4(0.f, 0.f, 0.f, 0.f);
    if (je > jb) {
      float inv = 1.f / ssum;
      ax *= inv; ay *= inv; az *= inv; aw *= inv;
      o.x = ax > 0.f ? ax : __expf(ax) - 1.f;
      o.y = ay > 0.f ? ay : __expf(ay) - 1.f;
      o.z = az > 0.f ? az : __expf(az) - 1.f;
      o.w = aw > 0.f ? aw : __expf(aw) - 1.f;
    }
    *(float4*)(out + ((size_t)node << 6) + cq) = o;
  }
}

extern "C" void kernel_launch(void* const* d_in, const int* in_sizes, int n_in,
                              void* d_out, int out_size, void* d_ws, size_t ws_size,
                              hipStream_t stream) {
  const float* h = (const float*)d_in[0];
  const float* W = (const float*)d_in[1];
  const float* a = (const float*)d_in[2];
  const int* src = (const int*)d_in[3];
  const int* dst = (const int*)d_in[4];
  const int n = in_sizes[0] / IN_DIM;  // 100000
  const int E = in_sizes[3];           // 1600000
  float* out = (float*)d_out;

  const int b1 = (E + CHUNK - 1) / CHUNK;         // 196
  const int nbuck = (n + (1 << BSH) - 1) >> BSH;  // 391

  char* ws = (char*)d_ws;
  auto alloc = [&](size_t bytes) {
    char* p = ws;
    ws += (bytes + 15) & ~(size_t)15;
    return p;
  };
  unsigned short* Wbf = (unsigned short*)alloc(16384 * 2);
  unsigned short* zb = (unsigned short*)alloc((size_t)n * OUT_DIM * 2);
  float* el = (float*)alloc((size_t)n * 4);
  float* er = (float*)alloc((size_t)n * 4);
  int* tot = (int*)alloc(512 * 4);
  int* pbeg = (int*)alloc(512 * 4);
  int* gcur = (int*)alloc(512 * 4);
  int* pairs = (int*)alloc((size_t)E * 4);

  k_prep<<<8, 256, 0, stream>>>(W, Wbf, tot);
  k_gemm<<<(n + 63) / 64, 256, 0, stream>>>(h, Wbf, a, zb, el, er, n, dst, tot, E, nbuck);
  k_scanT<<<1, 256, 0, stream>>>(tot, pbeg, gcur, nbuck);
  k_part<<<b1, 512, 0, stream>>>(src, dst, gcur, pairs, E, nbuck);
  k_p2agg<<<nbuck, 1024, 0, stream>>>(pairs, tot, pbeg, el, er, zb, out, n);
}

// Round 5
// 242.401 us; speedup vs baseline: 1.3855x; 1.0607x over previous
//
#include <hip/hip_runtime.h>
#include <hip/hip_bf16.h>

#define IN_DIM 256
#define OUT_DIM 64
#define CHUNK 8192
#define BSH 8      // bucket = dst >> 8 (256 nodes/bucket)
#define P2CAP 6144

typedef short bf16x8 __attribute__((ext_vector_type(8)));
typedef float f32x4 __attribute__((ext_vector_type(4)));

__device__ inline unsigned short f2bf(float x) {
  unsigned int u = __float_as_uint(x);
  return (unsigned short)((u + 0x7FFFu + ((u >> 16) & 1u)) >> 16);
}

#define GLOAD_LDS16(gp, lp)                                                        \
  __builtin_amdgcn_global_load_lds(                                                \
      (const __attribute__((address_space(1))) unsigned int*)(gp),                 \
      (__attribute__((address_space(3))) unsigned int*)(lp), 16, 0, 0)

// ---- prep: W [256][64] fp32 -> Wbf in MFMA-fragment-major bf16 -------------
// Also zeroes tot[] (per-bucket totals accumulated by k_gemm's hist tail).
__global__ __launch_bounds__(256) void k_prep(const float* __restrict__ W,
                                              unsigned short* __restrict__ Wbf,
                                              int* __restrict__ tot) {
  int f = blockIdx.x * 256 + threadIdx.x;  // 0..2047
  if (f < 512) tot[f] = 0;
  int kc = f >> 8, ct = (f >> 6) & 3, q = (f >> 4) & 3, nq = f & 15;
  int col = ct * 16 + nq, k0 = kc * 32 + q * 8;
  unsigned short v[8];
#pragma unroll
  for (int j = 0; j < 8; ++j) v[j] = f2bf(W[(size_t)(k0 + j) * OUT_DIM + col]);
  *(uint4*)(Wbf + (size_t)f * 8) = *(uint4*)v;
}

// ---- GEMM: zb(bf16) = h @ W ; el = z@a1 ; er = z@a2 -------------------------
// A tile staged fp32 via global_load_lds DMA (linear LDS dest, XOR-swizzled
// global source + matching swizzled ds_read -> conflict-free). All 32 W
// fragments preloaded to VGPRs. Tail: per-bucket degree totals.
__global__ __launch_bounds__(256) void k_gemm(const float* __restrict__ h,
                                              const unsigned short* __restrict__ Wbf,
                                              const float* __restrict__ a,
                                              unsigned short* __restrict__ zb,
                                              float* __restrict__ el,
                                              float* __restrict__ er, int n,
                                              const int* __restrict__ dst,
                                              int* __restrict__ tot, int E,
                                              int nbuck) {
  __shared__ __align__(16) float Af[64 * 256];  // 64 KB, LINEAR (DMA dest)
  __shared__ int hist[512];
  const int t = threadIdx.x;
  const int base = blockIdx.x * 64;
  const int w = t >> 6, lane = t & 63, nq = lane & 15, q = lane >> 4;

  // preload all W fragments (32 KB, L2-hot) into registers: 128 VGPR/lane.
  bf16x8 wf[8][4];
#pragma unroll
  for (int kc = 0; kc < 8; ++kc)
#pragma unroll
    for (int ct = 0; ct < 4; ++ct)
      wf[kc][ct] = *(const bf16x8*)(Wbf + (((kc * 4 + ct) * 64 + lane) << 3));

  // DMA-stage h tile: 4096 x 16B, fire-and-forget. LDS dest linear; global
  // source pre-swizzled so swizzled reads below see conflict-free banks.
#pragma unroll
  for (int i = 0; i < 16; ++i) {
    int f = i * 256 + t;
    int row = f >> 6;            // 0..63
    int cb = (f & 63) * 16;      // byte col within row
    int gcb = cb ^ ((row & 7) << 4);
    int grow = base + row;
    const char* gp = (grow < n) ? (const char*)h + ((size_t)grow * 1024 + gcb)
                                : (const char*)h;  // clamp: garbage, never used
    char* lp = (char*)Af + (size_t)(i * 4096 + w * 1024);  // wave-uniform base
    GLOAD_LDS16(gp, lp);
  }
  __syncthreads();

  f32x4 acc[4];
#pragma unroll
  for (int ct = 0; ct < 4; ++ct) acc[ct] = (f32x4){0.f, 0.f, 0.f, 0.f};

  const int rowb = w * 16 + nq;
  const char* Arow = (const char*)Af + rowb * 1024;
  const int sw = (rowb & 7) << 4;

#pragma unroll
  for (int kc = 0; kc < 8; ++kc) {
    int c0 = kc * 128 + q * 32;
    float4 lo = *(const float4*)(Arow + (c0 ^ sw));
    float4 hi = *(const float4*)(Arow + ((c0 + 16) ^ sw));
    bf16x8 af;
    af[0] = (short)f2bf(lo.x); af[1] = (short)f2bf(lo.y);
    af[2] = (short)f2bf(lo.z); af[3] = (short)f2bf(lo.w);
    af[4] = (short)f2bf(hi.x); af[5] = (short)f2bf(hi.y);
    af[6] = (short)f2bf(hi.z); af[7] = (short)f2bf(hi.w);
#pragma unroll
    for (int ct = 0; ct < 4; ++ct)
      acc[ct] = __builtin_amdgcn_mfma_f32_16x16x32_bf16(af, wf[kc][ct], acc[ct], 0, 0, 0);
  }

  // epilogue. C/D: col = ct*16 + nq, row-in-tile = q*4 + r.
  float a1[4], a2[4];
#pragma unroll
  for (int ct = 0; ct < 4; ++ct) {
    a1[ct] = a[ct * 16 + nq];
    a2[ct] = a[OUT_DIM + ct * 16 + nq];
  }
#pragma unroll
  for (int r = 0; r < 4; ++r) {
    int orow = base + w * 16 + q * 4 + r;
    float p1 = 0.f, p2 = 0.f;
#pragma unroll
    for (int ct = 0; ct < 4; ++ct) {
      float v = acc[ct][r];
      p1 += v * a1[ct];
      p2 += v * a2[ct];
      if (orow < n) zb[(size_t)orow * OUT_DIM + ct * 16 + nq] = f2bf(v);
    }
    p1 += __shfl_xor(p1, 1); p1 += __shfl_xor(p1, 2);
    p1 += __shfl_xor(p1, 4); p1 += __shfl_xor(p1, 8);
    p2 += __shfl_xor(p2, 1); p2 += __shfl_xor(p2, 2);
    p2 += __shfl_xor(p2, 4); p2 += __shfl_xor(p2, 8);
    if (orow < n && nq == 0) { el[orow] = p1; er[orow] = p2; }
  }

  // fused per-bucket totals: 1024 edges per block (grid 1563 covers E=1.6M).
  hist[t] = 0;
  hist[t + 256] = 0;
  __syncthreads();
  int e0 = blockIdx.x * 1024 + t * 4;
  if (e0 + 4 <= E) {
    int4 d4 = *(const int4*)(dst + e0);
    atomicAdd(&hist[d4.x >> BSH], 1);
    atomicAdd(&hist[d4.y >> BSH], 1);
    atomicAdd(&hist[d4.z >> BSH], 1);
    atomicAdd(&hist[d4.w >> BSH], 1);
  } else {
#pragma unroll
    for (int k = 0; k < 4; ++k) {
      int e = e0 + k;
      if (e < E) atomicAdd(&hist[dst[e] >> BSH], 1);
    }
  }
  __syncthreads();
  for (int i = t; i < nbuck; i += 256)
    if (hist[i]) atomicAdd(&tot[i], hist[i]);
}

// ---- tiny scan: tot -> pbeg (exclusive) and seed gcur = pbeg ---------------
__global__ __launch_bounds__(256) void k_scanT(const int* __restrict__ tot,
                                               int* __restrict__ pbeg,
                                               int* __restrict__ gcur, int nbuck) {
  __shared__ int wtot[4];
  int t = threadIdx.x;
  int d0 = (2 * t < nbuck) ? tot[2 * t] : 0;
  int d1 = (2 * t + 1 < nbuck) ? tot[2 * t + 1] : 0;
  int tsum = d0 + d1;
  int lane = t & 63, w = t >> 6;
  int incl = tsum;
  for (int o = 1; o < 64; o <<= 1) {
    int u = __shfl_up(incl, o);
    if (lane >= o) incl += u;
  }
  if (lane == 63) wtot[w] = incl;
  __syncthreads();
  int woff = 0;
  for (int i = 0; i < 4; ++i)
    if (i < w) woff += wtot[i];
  int ex = woff + incl - tsum;
  pbeg[2 * t] = ex;
  gcur[2 * t] = ex;
  pbeg[2 * t + 1] = ex + d0;
  gcur[2 * t + 1] = ex + d0;
}

// ---- partition: LDS bucket-sort 8192-edge chunk, atomic-reserve runs, -------
// dump run-contiguous into bucket-major pairs[]. No scattered global stores.
__global__ __launch_bounds__(512) void k_part(const int* __restrict__ src,
                                              const int* __restrict__ dst,
                                              int* __restrict__ gcur,
                                              int* __restrict__ pairs, int E,
                                              int nbuck) {
  __shared__ int hist[512];
  __shared__ int excl[512];
  __shared__ int cur[512];
  __shared__ int rbase[512];
  __shared__ int stage[CHUNK];           // 32 KB
  __shared__ unsigned short sbk[CHUNK];  // 16 KB: bucket id per sorted slot
  __shared__ int wtot[8];
  const int t = threadIdx.x, b = blockIdx.x;
  const int beg = b * CHUNK;
  const int cnt = min(CHUNK, E - beg);

  hist[t] = 0;
  __syncthreads();

  int dv[16], sv[16];
#pragma unroll
  for (int k = 0; k < 16; ++k) {
    int i = k * 512 + t;
    dv[k] = -1;
    if (i < cnt) {
      dv[k] = dst[beg + i];
      sv[k] = src[beg + i];
      atomicAdd(&hist[dv[k] >> BSH], 1);
    }
  }
  __syncthreads();

  // exclusive scan of hist[512] (1 elem/thread, 8 waves) + run reservation.
  {
    int v = hist[t];
    int lane = t & 63, w = t >> 6;
    int incl = v;
    for (int o = 1; o < 64; o <<= 1) {
      int u = __shfl_up(incl, o);
      if (lane >= o) incl += u;
    }
    if (lane == 63) wtot[w] = incl;
    __syncthreads();
    int woff = 0;
    for (int i = 0; i < 8; ++i)
      if (i < w) woff += wtot[i];
    int ex = woff + incl - v;
    excl[t] = ex;
    cur[t] = ex;
    if (t < nbuck && v > 0) rbase[t] = atomicAdd(&gcur[t], v);
  }
  __syncthreads();

  // LDS scatter (banked) into bucket-sorted order.
#pragma unroll
  for (int k = 0; k < 16; ++k) {
    if (dv[k] >= 0) {
      int bk = dv[k] >> BSH;
      int r = atomicAdd(&cur[bk], 1);
      stage[r] = ((dv[k] & ((1 << BSH) - 1)) << 24) | sv[k];
      sbk[r] = (unsigned short)bk;
    }
  }
  __syncthreads();

  // dump: consecutive slots within a run -> consecutive global dest (coalesced).
  for (int i = t; i < cnt; i += 512) {
    int bk = sbk[i];
    pairs[rbase[bk] + (i - excl[bk])] = stage[i];
  }
}

// ---- fused pass-2 + aggregation: bucket sort in LDS, aggregate from LDS -----
__global__ __launch_bounds__(1024) void k_p2agg(const int* __restrict__ pairs,
                                                const int* __restrict__ tot,
                                                const int* __restrict__ pbeg,
                                                const float* __restrict__ el,
                                                const float* __restrict__ er,
                                                const unsigned short* __restrict__ zb,
                                                float* __restrict__ out, int n) {
  __shared__ int deg[256];
  __shared__ int loff[257];
  __shared__ int cur[256];
  __shared__ int stage[P2CAP];
  __shared__ int wtot[4];
  const int t = threadIdx.x, b = blockIdx.x;
  const int beg = pbeg[b];
  const int cnt = tot[b];

  if (t < 256) deg[t] = 0;
  __syncthreads();

  // single coalesced read of this bucket's edges into registers + degree hist.
  int pv[6];
#pragma unroll
  for (int k = 0; k < 6; ++k) {
    int i = k * 1024 + t;
    pv[k] = 0;
    if (i < cnt) {
      pv[k] = pairs[beg + i];
      atomicAdd(&deg[((unsigned)pv[k]) >> 24], 1);
    }
  }
  __syncthreads();

  // exclusive scan of deg[256] by the first 4 waves.
  int v = 0, inc = 0;
  const int lane = t & 63, w = t >> 6;
  if (t < 256) {
    v = deg[t];
    inc = v;
    for (int o = 1; o < 64; o <<= 1) {
      int u = __shfl_up(inc, o);
      if (lane >= o) inc += u;
    }
    if (lane == 63) wtot[w] = inc;
  }
  __syncthreads();
  if (t < 256) {
    int woff = 0;
    for (int i = 0; i < 4; ++i)
      if (i < w) woff += wtot[i];
    int ex = woff + inc - v;
    loff[t] = ex;
    cur[t] = ex;
    if (t == 255) loff[256] = ex + v;
  }
  __syncthreads();

  // scatter into node-sorted LDS stage (payload = src only).
#pragma unroll
  for (int k = 0; k < 6; ++k) {
    int i = k * 1024 + t;
    if (i < cnt) {
      int r = atomicAdd(&cur[((unsigned)pv[k]) >> 24], 1);
      if (r < P2CAP) stage[r] = pv[k] & 0xFFFFFF;
    }
  }
  __syncthreads();

  // aggregation: 64 groups x 16 lanes; 4 rounds cover 256 nodes.
  const int g = t >> 4;
  const int cq = (t & 15) * 4;
#pragma unroll
  for (int round = 0; round < 4; ++round) {
    int nl = round * 64 + g;
    int node = (b << BSH) + nl;
    if (node >= n) continue;
    int jb = loff[nl], je = loff[nl + 1];
    float erd = er[node];
    float ax = 0.f, ay = 0.f, az = 0.f, aw = 0.f, ssum = 0.f;
    int j = jb;
    for (; j + 4 <= je; j += 4) {
      int s0 = stage[j], s1 = stage[j + 1], s2 = stage[j + 2], s3 = stage[j + 3];
      uint2 z0 = *(const uint2*)(zb + (s0 << 6) + cq);
      uint2 z1 = *(const uint2*)(zb + (s1 << 6) + cq);
      uint2 z2 = *(const uint2*)(zb + (s2 << 6) + cq);
      uint2 z3 = *(const uint2*)(zb + (s3 << 6) + cq);
      float x0 = el[s0] + erd, x1 = el[s1] + erd;
      float x2 = el[s2] + erd, x3 = el[s3] + erd;
      x0 = x0 > 0.f ? x0 : 0.01f * x0;
      x1 = x1 > 0.f ? x1 : 0.01f * x1;
      x2 = x2 > 0.f ? x2 : 0.01f * x2;
      x3 = x3 > 0.f ? x3 : 0.01f * x3;
      float e0 = __expf(x0), e1 = __expf(x1), e2 = __expf(x2), e3 = __expf(x3);
      ssum += (e0 + e1) + (e2 + e3);
      ax += e0 * __uint_as_float(z0.x << 16) + e1 * __uint_as_float(z1.x << 16) +
            e2 * __uint_as_float(z2.x << 16) + e3 * __uint_as_float(z3.x << 16);
      ay += e0 * __uint_as_float(z0.x & 0xFFFF0000u) + e1 * __uint_as_float(z1.x & 0xFFFF0000u) +
            e2 * __uint_as_float(z2.x & 0xFFFF0000u) + e3 * __uint_as_float(z3.x & 0xFFFF0000u);
      az += e0 * __uint_as_float(z0.y << 16) + e1 * __uint_as_float(z1.y << 16) +
            e2 * __uint_as_float(z2.y << 16) + e3 * __uint_as_float(z3.y << 16);
      aw += e0 * __uint_as_float(z0.y & 0xFFFF0000u) + e1 * __uint_as_float(z1.y & 0xFFFF0000u) +
            e2 * __uint_as_float(z2.y & 0xFFFF0000u) + e3 * __uint_as_float(z3.y & 0xFFFF0000u);
    }
    for (; j < je; ++j) {
      int s = stage[j];
      uint2 zv = *(const uint2*)(zb + (s << 6) + cq);
      float x = el[s] + erd;
      x = x > 0.f ? x : 0.01f * x;
      float ex = __expf(x);
      ssum += ex;
      ax += ex * __uint_as_float(zv.x << 16);
      ay += ex * __uint_as_float(zv.x & 0xFFFF0000u);
      az += ex * __uint_as_float(zv.y << 16);
      aw += ex * __uint_as_float(zv.y & 0xFFFF0000u);
    }
    float4 o = make_float4(0.f, 0.f, 0.f, 0.f);
    if (je > jb) {
      float inv = 1.f / ssum;
      ax *= inv; ay *= inv; az *= inv; aw *= inv;
      o.x = ax > 0.f ? ax : __expf(ax) - 1.f;
      o.y = ay > 0.f ? ay : __expf(ay) - 1.f;
      o.z = az > 0.f ? az : __expf(az) - 1.f;
      o.w = aw > 0.f ? aw : __expf(aw) - 1.f;
    }
    *(float4*)(out + ((size_t)node << 6) + cq) = o;
  }
}

extern "C" void kernel_launch(void* const* d_in, const int* in_sizes, int n_in,
                              void* d_out, int out_size, void* d_ws, size_t ws_size,
                              hipStream_t stream) {
  const float* h = (const float*)d_in[0];
  const float* W = (const float*)d_in[1];
  const float* a = (const float*)d_in[2];
  const int* src = (const int*)d_in[3];
  const int* dst = (const int*)d_in[4];
  const int n = in_sizes[0] / IN_DIM;  // 100000
  const int E = in_sizes[3];           // 1600000
  float* out = (float*)d_out;

  const int b1 = (E + CHUNK - 1) / CHUNK;         // 196
  const int nbuck = (n + (1 << BSH) - 1) >> BSH;  // 391

  char* ws = (char*)d_ws;
  auto alloc = [&](size_t bytes) {
    char* p = ws;
    ws += (bytes + 15) & ~(size_t)15;
    return p;
  };
  unsigned short* Wbf = (unsigned short*)alloc(16384 * 2);
  unsigned short* zb = (unsigned short*)alloc((size_t)n * OUT_DIM * 2);
  float* el = (float*)alloc((size_t)n * 4);
  float* er = (float*)alloc((size_t)n * 4);
  int* tot = (int*)alloc(512 * 4);
  int* pbeg = (int*)alloc(512 * 4);
  int* gcur = (int*)alloc(512 * 4);
  int* pairs = (int*)alloc((size_t)E * 4);

  k_prep<<<8, 256, 0, stream>>>(W, Wbf, tot);
  k_gemm<<<(n + 63) / 64, 256, 0, stream>>>(h, Wbf, a, zb, el, er, n, dst, tot, E, nbuck);
  k_scanT<<<1, 256, 0, stream>>>(tot, pbeg, gcur, nbuck);
  k_part<<<b1, 512, 0, stream>>>(src, dst, gcur, pairs, E, nbuck);
  k_p2agg<<<nbuck, 1024, 0, stream>>>(pairs, tot, pbeg, el, er, zb, out, n);
}

// Round 6
// 241.980 us; speedup vs baseline: 1.3880x; 1.0017x over previous
//
#include <hip/hip_runtime.h>
#include <hip/hip_bf16.h>

#define IN_DIM 256
#define OUT_DIM 64
#define CHUNK 8192
#define BSH 8      // bucket = dst >> 8 (256 nodes/bucket)
#define P2CAP 6144

typedef short bf16x8 __attribute__((ext_vector_type(8)));
typedef float f32x4 __attribute__((ext_vector_type(4)));

__device__ inline unsigned short f2bf(float x) {
  unsigned int u = __float_as_uint(x);
  return (unsigned short)((u + 0x7FFFu + ((u >> 16) & 1u)) >> 16);
}

#define GLOAD_LDS16(gp, lp)                                                        \
  __builtin_amdgcn_global_load_lds(                                                \
      (const __attribute__((address_space(1))) unsigned int*)(gp),                 \
      (__attribute__((address_space(3))) unsigned int*)(lp), 16, 0, 0)

// ---- prep: W [256][64] fp32 -> Wbf in MFMA-fragment-major bf16 -------------
// Also zeroes tot[] (per-bucket totals accumulated by k_gemm's hist tail).
__global__ __launch_bounds__(256) void k_prep(const float* __restrict__ W,
                                              unsigned short* __restrict__ Wbf,
                                              int* __restrict__ tot) {
  int f = blockIdx.x * 256 + threadIdx.x;  // 0..2047
  if (f < 512) tot[f] = 0;
  int kc = f >> 8, ct = (f >> 6) & 3, q = (f >> 4) & 3, nq = f & 15;
  int col = ct * 16 + nq, k0 = kc * 32 + q * 8;
  unsigned short v[8];
#pragma unroll
  for (int j = 0; j < 8; ++j) v[j] = f2bf(W[(size_t)(k0 + j) * OUT_DIM + col]);
  *(uint4*)(Wbf + (size_t)f * 8) = *(uint4*)v;
}

// ---- persistent pipelined GEMM: zb = h@W (bf16), el/er projections ----------
// 256 blocks (1/CU, 130 KB LDS). Each block grid-strides ~6 row-tiles with
// double-buffered DMA staging: issue next tile's global_load_lds, counted
// s_waitcnt vmcnt(16) (never 0 mid-loop), RAW s_barrier (no implicit drain),
// compute, lgkmcnt(0)+barrier, swap. W fragments resident in VGPRs (LB(256,1)).
// Tail: per-block LDS hist over ~6.2K edges -> one 391-atomic flush.
__global__ __launch_bounds__(256, 1) void k_gemm(const float* __restrict__ h,
                                                 const unsigned short* __restrict__ Wbf,
                                                 const float* __restrict__ a,
                                                 unsigned short* __restrict__ zb,
                                                 float* __restrict__ el,
                                                 float* __restrict__ er, int n,
                                                 const int* __restrict__ dst,
                                                 int* __restrict__ tot, int E,
                                                 int nbuck) {
  __shared__ __align__(16) float Af[2][64 * 256];  // 128 KB double buffer
  __shared__ int hist[512];
  const int t = threadIdx.x;
  const int w = t >> 6, lane = t & 63, nq = lane & 15, q = lane >> 4;
  const int nt = (n + 63) >> 6;
  const int G = gridDim.x;

  // W fragments: loaded ONCE, resident (128 VGPR).
  bf16x8 wf[8][4];
#pragma unroll
  for (int kc = 0; kc < 8; ++kc)
#pragma unroll
    for (int ct = 0; ct < 4; ++ct)
      wf[kc][ct] = *(const bf16x8*)(Wbf + (((kc * 4 + ct) * 64 + lane) << 3));

  float a1[4], a2[4];
#pragma unroll
  for (int ct = 0; ct < 4; ++ct) {
    a1[ct] = a[ct * 16 + nq];
    a2[ct] = a[OUT_DIM + ct * 16 + nq];
  }

  // stage: 64 rows x 1 KB, linear LDS dest (DMA), XOR-swizzled global source.
  auto stage = [&](int bsel, int tile) {
    const int base = tile << 6;
#pragma unroll
    for (int i = 0; i < 16; ++i) {
      int f = i * 256 + t;
      int row = f >> 6;
      int cb = (f & 63) * 16;
      int gcb = cb ^ ((row & 7) << 4);
      int grow = base + row;
      const char* gp = (grow < n) ? (const char*)h + ((size_t)grow * 1024 + gcb)
                                  : (const char*)h;  // clamp: garbage, never used
      char* lp = (char*)&Af[bsel][0] + (i * 4096 + w * 1024);  // wave-uniform
      GLOAD_LDS16(gp, lp);
    }
  };

  const int rowb = w * 16 + nq;
  const int sw = (rowb & 7) << 4;

  int cur = 0;
  stage(0, blockIdx.x);
  for (int tile = blockIdx.x; tile < nt; tile += G) {
    int nxt = tile + G;
    if (nxt < nt) {
      stage(cur ^ 1, nxt);
      // ops retire in issue order: <=16 outstanding => cur tile's 16 DMAs done,
      // next tile's 16 still in flight.
      asm volatile("s_waitcnt vmcnt(16)" ::: "memory");
    } else {
      asm volatile("s_waitcnt vmcnt(0)" ::: "memory");
    }
    __builtin_amdgcn_sched_barrier(0);
    __builtin_amdgcn_s_barrier();  // raw: no implicit vmcnt(0) drain

    const char* Arow = (const char*)&Af[cur][0] + rowb * 1024;
    f32x4 acc[4];
#pragma unroll
    for (int ct = 0; ct < 4; ++ct) acc[ct] = (f32x4){0.f, 0.f, 0.f, 0.f};
#pragma unroll
    for (int kc = 0; kc < 8; ++kc) {
      int c0 = kc * 128 + q * 32;
      float4 lo = *(const float4*)(Arow + (c0 ^ sw));
      float4 hi = *(const float4*)(Arow + ((c0 + 16) ^ sw));
      bf16x8 af;
      af[0] = (short)f2bf(lo.x); af[1] = (short)f2bf(lo.y);
      af[2] = (short)f2bf(lo.z); af[3] = (short)f2bf(lo.w);
      af[4] = (short)f2bf(hi.x); af[5] = (short)f2bf(hi.y);
      af[6] = (short)f2bf(hi.z); af[7] = (short)f2bf(hi.w);
#pragma unroll
      for (int ct = 0; ct < 4; ++ct)
        acc[ct] = __builtin_amdgcn_mfma_f32_16x16x32_bf16(af, wf[kc][ct], acc[ct], 0, 0, 0);
    }

    const int base = tile << 6;
#pragma unroll
    for (int r = 0; r < 4; ++r) {
      int orow = base + w * 16 + q * 4 + r;
      float p1 = 0.f, p2 = 0.f;
#pragma unroll
      for (int ct = 0; ct < 4; ++ct) {
        float v = acc[ct][r];
        p1 += v * a1[ct];
        p2 += v * a2[ct];
        if (orow < n) zb[(size_t)orow * OUT_DIM + ct * 16 + nq] = f2bf(v);
      }
      p1 += __shfl_xor(p1, 1); p1 += __shfl_xor(p1, 2);
      p1 += __shfl_xor(p1, 4); p1 += __shfl_xor(p1, 8);
      p2 += __shfl_xor(p2, 1); p2 += __shfl_xor(p2, 2);
      p2 += __shfl_xor(p2, 4); p2 += __shfl_xor(p2, 8);
      if (orow < n && nq == 0) { el[orow] = p1; er[orow] = p2; }
    }

    asm volatile("s_waitcnt lgkmcnt(0)" ::: "memory");
    __builtin_amdgcn_s_barrier();  // readers done before next stage overwrites
    cur ^= 1;
  }

  // per-bucket totals: persistent block covers one contiguous edge range.
  hist[t] = 0;
  hist[t + 256] = 0;
  __syncthreads();
  const int ER = (((E + G - 1) / G) + 3) & ~3;  // int4-aligned range
  const int ebeg = blockIdx.x * ER;
  const int eend = min(E, ebeg + ER);
  for (int e0 = ebeg + t * 4; e0 < eend; e0 += 1024) {
    if (e0 + 4 <= eend) {
      int4 d4 = *(const int4*)(dst + e0);
      atomicAdd(&hist[d4.x >> BSH], 1);
      atomicAdd(&hist[d4.y >> BSH], 1);
      atomicAdd(&hist[d4.z >> BSH], 1);
      atomicAdd(&hist[d4.w >> BSH], 1);
    } else {
#pragma unroll
      for (int k = 0; k < 4; ++k)
        if (e0 + k < eend) atomicAdd(&hist[dst[e0 + k] >> BSH], 1);
    }
  }
  __syncthreads();
  for (int i = t; i < nbuck; i += 256)
    if (hist[i]) atomicAdd(&tot[i], hist[i]);
}

// ---- tiny scan: tot -> pbeg (exclusive) and seed gcur = pbeg ---------------
__global__ __launch_bounds__(256) void k_scanT(const int* __restrict__ tot,
                                               int* __restrict__ pbeg,
                                               int* __restrict__ gcur, int nbuck) {
  __shared__ int wtot[4];
  int t = threadIdx.x;
  int d0 = (2 * t < nbuck) ? tot[2 * t] : 0;
  int d1 = (2 * t + 1 < nbuck) ? tot[2 * t + 1] : 0;
  int tsum = d0 + d1;
  int lane = t & 63, w = t >> 6;
  int incl = tsum;
  for (int o = 1; o < 64; o <<= 1) {
    int u = __shfl_up(incl, o);
    if (lane >= o) incl += u;
  }
  if (lane == 63) wtot[w] = incl;
  __syncthreads();
  int woff = 0;
  for (int i = 0; i < 4; ++i)
    if (i < w) woff += wtot[i];
  int ex = woff + incl - tsum;
  pbeg[2 * t] = ex;
  gcur[2 * t] = ex;
  pbeg[2 * t + 1] = ex + d0;
  gcur[2 * t + 1] = ex + d0;
}

// ---- partition: LDS bucket-sort 8192-edge chunk, atomic-reserve runs, -------
// dump run-contiguous into bucket-major pairs[]. No scattered global stores.
__global__ __launch_bounds__(512) void k_part(const int* __restrict__ src,
                                              const int* __restrict__ dst,
                                              int* __restrict__ gcur,
                                              int* __restrict__ pairs, int E,
                                              int nbuck) {
  __shared__ int hist[512];
  __shared__ int excl[512];
  __shared__ int cur[512];
  __shared__ int rbase[512];
  __shared__ int stage[CHUNK];           // 32 KB
  __shared__ unsigned short sbk[CHUNK];  // 16 KB: bucket id per sorted slot
  __shared__ int wtot[8];
  const int t = threadIdx.x, b = blockIdx.x;
  const int beg = b * CHUNK;
  const int cnt = min(CHUNK, E - beg);

  hist[t] = 0;
  __syncthreads();

  int dv[16], sv[16];
#pragma unroll
  for (int k = 0; k < 16; ++k) {
    int i = k * 512 + t;
    dv[k] = -1;
    if (i < cnt) {
      dv[k] = dst[beg + i];
      sv[k] = src[beg + i];
      atomicAdd(&hist[dv[k] >> BSH], 1);
    }
  }
  __syncthreads();

  // exclusive scan of hist[512] (1 elem/thread, 8 waves) + run reservation.
  {
    int v = hist[t];
    int lane = t & 63, w = t >> 6;
    int incl = v;
    for (int o = 1; o < 64; o <<= 1) {
      int u = __shfl_up(incl, o);
      if (lane >= o) incl += u;
    }
    if (lane == 63) wtot[w] = incl;
    __syncthreads();
    int woff = 0;
    for (int i = 0; i < 8; ++i)
      if (i < w) woff += wtot[i];
    int ex = woff + incl - v;
    excl[t] = ex;
    cur[t] = ex;
    if (t < nbuck && v > 0) rbase[t] = atomicAdd(&gcur[t], v);
  }
  __syncthreads();

  // LDS scatter (banked) into bucket-sorted order.
#pragma unroll
  for (int k = 0; k < 16; ++k) {
    if (dv[k] >= 0) {
      int bk = dv[k] >> BSH;
      int r = atomicAdd(&cur[bk], 1);
      stage[r] = ((dv[k] & ((1 << BSH) - 1)) << 24) | sv[k];
      sbk[r] = (unsigned short)bk;
    }
  }
  __syncthreads();

  // dump: consecutive slots within a run -> consecutive global dest (coalesced).
  for (int i = t; i < cnt; i += 512) {
    int bk = sbk[i];
    pairs[rbase[bk] + (i - excl[bk])] = stage[i];
  }
}

// ---- fused pass-2 + aggregation: bucket sort in LDS, aggregate from LDS -----
__global__ __launch_bounds__(1024) void k_p2agg(const int* __restrict__ pairs,
                                                const int* __restrict__ tot,
                                                const int* __restrict__ pbeg,
                                                const float* __restrict__ el,
                                                const float* __restrict__ er,
                                                const unsigned short* __restrict__ zb,
                                                float* __restrict__ out, int n) {
  __shared__ int deg[256];
  __shared__ int loff[257];
  __shared__ int cur[256];
  __shared__ int stage[P2CAP];
  __shared__ int wtot[4];
  const int t = threadIdx.x, b = blockIdx.x;
  const int beg = pbeg[b];
  const int cnt = tot[b];

  if (t < 256) deg[t] = 0;
  __syncthreads();

  // single coalesced read of this bucket's edges into registers + degree hist.
  int pv[6];
#pragma unroll
  for (int k = 0; k < 6; ++k) {
    int i = k * 1024 + t;
    pv[k] = 0;
    if (i < cnt) {
      pv[k] = pairs[beg + i];
      atomicAdd(&deg[((unsigned)pv[k]) >> 24], 1);
    }
  }
  __syncthreads();

  // exclusive scan of deg[256] by the first 4 waves.
  int v = 0, inc = 0;
  const int lane = t & 63, w = t >> 6;
  if (t < 256) {
    v = deg[t];
    inc = v;
    for (int o = 1; o < 64; o <<= 1) {
      int u = __shfl_up(inc, o);
      if (lane >= o) inc += u;
    }
    if (lane == 63) wtot[w] = inc;
  }
  __syncthreads();
  if (t < 256) {
    int woff = 0;
    for (int i = 0; i < 4; ++i)
      if (i < w) woff += wtot[i];
    int ex = woff + inc - v;
    loff[t] = ex;
    cur[t] = ex;
    if (t == 255) loff[256] = ex + v;
  }
  __syncthreads();

  // scatter into node-sorted LDS stage (payload = src only).
#pragma unroll
  for (int k = 0; k < 6; ++k) {
    int i = k * 1024 + t;
    if (i < cnt) {
      int r = atomicAdd(&cur[((unsigned)pv[k]) >> 24], 1);
      if (r < P2CAP) stage[r] = pv[k] & 0xFFFFFF;
    }
  }
  __syncthreads();

  // aggregation: 64 groups x 16 lanes; 4 rounds cover 256 nodes.
  const int g = t >> 4;
  const int cq = (t & 15) * 4;
#pragma unroll
  for (int round = 0; round < 4; ++round) {
    int nl = round * 64 + g;
    int node = (b << BSH) + nl;
    if (node >= n) continue;
    int jb = loff[nl], je = loff[nl + 1];
    float erd = er[node];
    float ax = 0.f, ay = 0.f, az = 0.f, aw = 0.f, ssum = 0.f;
    int j = jb;
    for (; j + 4 <= je; j += 4) {
      int s0 = stage[j], s1 = stage[j + 1], s2 = stage[j + 2], s3 = stage[j + 3];
      uint2 z0 = *(const uint2*)(zb + (s0 << 6) + cq);
      uint2 z1 = *(const uint2*)(zb + (s1 << 6) + cq);
      uint2 z2 = *(const uint2*)(zb + (s2 << 6) + cq);
      uint2 z3 = *(const uint2*)(zb + (s3 << 6) + cq);
      float x0 = el[s0] + erd, x1 = el[s1] + erd;
      float x2 = el[s2] + erd, x3 = el[s3] + erd;
      x0 = x0 > 0.f ? x0 : 0.01f * x0;
      x1 = x1 > 0.f ? x1 : 0.01f * x1;
      x2 = x2 > 0.f ? x2 : 0.01f * x2;
      x3 = x3 > 0.f ? x3 : 0.01f * x3;
      float e0 = __expf(x0), e1 = __expf(x1), e2 = __expf(x2), e3 = __expf(x3);
      ssum += (e0 + e1) + (e2 + e3);
      ax += e0 * __uint_as_float(z0.x << 16) + e1 * __uint_as_float(z1.x << 16) +
            e2 * __uint_as_float(z2.x << 16) + e3 * __uint_as_float(z3.x << 16);
      ay += e0 * __uint_as_float(z0.x & 0xFFFF0000u) + e1 * __uint_as_float(z1.x & 0xFFFF0000u) +
            e2 * __uint_as_float(z2.x & 0xFFFF0000u) + e3 * __uint_as_float(z3.x & 0xFFFF0000u);
      az += e0 * __uint_as_float(z0.y << 16) + e1 * __uint_as_float(z1.y << 16) +
            e2 * __uint_as_float(z2.y << 16) + e3 * __uint_as_float(z3.y << 16);
      aw += e0 * __uint_as_float(z0.y & 0xFFFF0000u) + e1 * __uint_as_float(z1.y & 0xFFFF0000u) +
            e2 * __uint_as_float(z2.y & 0xFFFF0000u) + e3 * __uint_as_float(z3.y & 0xFFFF0000u);
    }
    for (; j < je; ++j) {
      int s = stage[j];
      uint2 zv = *(const uint2*)(zb + (s << 6) + cq);
      float x = el[s] + erd;
      x = x > 0.f ? x : 0.01f * x;
      float ex = __expf(x);
      ssum += ex;
      ax += ex * __uint_as_float(zv.x << 16);
      ay += ex * __uint_as_float(zv.x & 0xFFFF0000u);
      az += ex * __uint_as_float(zv.y << 16);
      aw += ex * __uint_as_float(zv.y & 0xFFFF0000u);
    }
    float4 o = make_float4(0.f, 0.f, 0.f, 0.f);
    if (je > jb) {
      float inv = 1.f / ssum;
      ax *= inv; ay *= inv; az *= inv; aw *= inv;
      o.x = ax > 0.f ? ax : __expf(ax) - 1.f;
      o.y = ay > 0.f ? ay : __expf(ay) - 1.f;
      o.z = az > 0.f ? az : __expf(az) - 1.f;
      o.w = aw > 0.f ? aw : __expf(aw) - 1.f;
    }
    *(float4*)(out + ((size_t)node << 6) + cq) = o;
  }
}

extern "C" void kernel_launch(void* const* d_in, const int* in_sizes, int n_in,
                              void* d_out, int out_size, void* d_ws, size_t ws_size,
                              hipStream_t stream) {
  const float* h = (const float*)d_in[0];
  const float* W = (const float*)d_in[1];
  const float* a = (const float*)d_in[2];
  const int* src = (const int*)d_in[3];
  const int* dst = (const int*)d_in[4];
  const int n = in_sizes[0] / IN_DIM;  // 100000
  const int E = in_sizes[3];           // 1600000
  float* out = (float*)d_out;

  const int b1 = (E + CHUNK - 1) / CHUNK;         // 196
  const int nbuck = (n + (1 << BSH) - 1) >> BSH;  // 391

  char* ws = (char*)d_ws;
  auto alloc = [&](size_t bytes) {
    char* p = ws;
    ws += (bytes + 15) & ~(size_t)15;
    return p;
  };
  unsigned short* Wbf = (unsigned short*)alloc(16384 * 2);
  unsigned short* zb = (unsigned short*)alloc((size_t)n * OUT_DIM * 2);
  float* el = (float*)alloc((size_t)n * 4);
  float* er = (float*)alloc((size_t)n * 4);
  int* tot = (int*)alloc(512 * 4);
  int* pbeg = (int*)alloc(512 * 4);
  int* gcur = (int*)alloc(512 * 4);
  int* pairs = (int*)alloc((size_t)E * 4);

  k_prep<<<8, 256, 0, stream>>>(W, Wbf, tot);
  k_gemm<<<256, 256, 0, stream>>>(h, Wbf, a, zb, el, er, n, dst, tot, E, nbuck);
  k_scanT<<<1, 256, 0, stream>>>(tot, pbeg, gcur, nbuck);
  k_part<<<b1, 512, 0, stream>>>(src, dst, gcur, pairs, E, nbuck);
  k_p2agg<<<nbuck, 1024, 0, stream>>>(pairs, tot, pbeg, el, er, zb, out, n);
}